// Round 13
// baseline (194.061 us; speedup 1.0000x reference)
//
#include <hip/hip_runtime.h>
#include <hip/hip_bf16.h>

using bf16_t = __bf16;
using bf16x4 = __attribute__((ext_vector_type(4))) __bf16;
using bf16x8 = __attribute__((ext_vector_type(8))) __bf16;
using f32x4  = __attribute__((ext_vector_type(4))) float;
using f32x16 = __attribute__((ext_vector_type(16))) float;
using u32x2  = __attribute__((ext_vector_type(2))) unsigned;

#define N_TOK 4096
#define DM    1024
#define NH    16
#define HD    64
#define D3    3072

// raw v_exp_f32 (skip OCML's denormal-range fixup; inputs bounded >> -126)
#if __has_builtin(__builtin_amdgcn_exp2f)
#define EXP2(x) __builtin_amdgcn_exp2f(x)
#else
extern "C" float __ocml_native_exp2_f32(float);
#define EXP2(x) __ocml_native_exp2_f32(x)
#endif

// ---------------------------------------------------------------- helpers
__device__ __forceinline__ void gl_lds16(const void* g, void* l) {
  __builtin_amdgcn_global_load_lds((const __attribute__((address_space(1))) void*)g,
                                   (__attribute__((address_space(3))) void*)l, 16, 0, 0);
}

__device__ __forceinline__ unsigned pkbf(float a, float b) {
  unsigned short la = __builtin_bit_cast(unsigned short, (bf16_t)a);
  unsigned short lb = __builtin_bit_cast(unsigned short, (bf16_t)b);
  return (unsigned)la | ((unsigned)lb << 16);
}

__device__ __forceinline__ bf16x8 mk8(unsigned a, unsigned b, unsigned c, unsigned d) {
  union { unsigned u[4]; bf16x8 v; } t;
  t.u[0] = a; t.u[1] = b; t.u[2] = c; t.u[3] = d;
  return t.v;
}

// softmax for one 32-kv block held as f32x16 (32x32 C-layout), producing the
// two 16-kv A-fragment slices for PV via pack + permlane32_swap (T12).
// l is NOT summed here: it is accumulated on the MFMA pipe via a ones-vector.
__device__ __forceinline__ void softmax_blk(const f32x16& sv, bf16x8& apA, bf16x8& apB) {
  float pp[16];
  #pragma unroll
  for (int r = 0; r < 16; r++) pp[r] = EXP2(sv[r]);
  unsigned w00 = pkbf(pp[0], pp[1]),   w01 = pkbf(pp[2], pp[3]);
  unsigned w10 = pkbf(pp[4], pp[5]),   w11 = pkbf(pp[6], pp[7]);
  unsigned w20 = pkbf(pp[8], pp[9]),   w21 = pkbf(pp[10], pp[11]);
  unsigned w30 = pkbf(pp[12], pp[13]), w31 = pkbf(pp[14], pp[15]);
  u32x2 r00 = __builtin_amdgcn_permlane32_swap(w00, w10, false, false);
  u32x2 r01 = __builtin_amdgcn_permlane32_swap(w01, w11, false, false);
  u32x2 r10 = __builtin_amdgcn_permlane32_swap(w20, w30, false, false);
  u32x2 r11 = __builtin_amdgcn_permlane32_swap(w21, w31, false, false);
  apA = mk8(r00[0], r01[0], r00[1], r01[1]);   // slice p=0 (kv +0..15)
  apB = mk8(r10[0], r11[0], r10[1], r11[1]);   // slice p=1 (kv +16..31)
}

// ---------------------------------------------------------------- prep kernels
__global__ void k_cvt_x(const float* __restrict__ x, bf16_t* __restrict__ xb) {
  int i = (blockIdx.x * blockDim.x + threadIdx.x) * 8;
  float4 f0 = *(const float4*)(x + i);
  float4 f1 = *(const float4*)(x + i + 4);
  bf16x8 v;
  v[0] = (bf16_t)f0.x; v[1] = (bf16_t)f0.y; v[2] = (bf16_t)f0.z; v[3] = (bf16_t)f0.w;
  v[4] = (bf16_t)f1.x; v[5] = (bf16_t)f1.y; v[6] = (bf16_t)f1.z; v[7] = (bf16_t)f1.w;
  *(bf16x8*)(xb + i) = v;
}

// in [R][C] f32  ->  out [C][R] bf16
__global__ void k_transpose_cvt(const float* __restrict__ in, bf16_t* __restrict__ outh,
                                int R, int C) {
  __shared__ float tile[64][65];
  int r0 = blockIdx.y * 64, c0 = blockIdx.x * 64;
  int t = threadIdx.x;
  #pragma unroll
  for (int i = 0; i < 16; i++) {
    int idx = i * 256 + t; int r = idx >> 6, c = idx & 63;
    tile[r][c] = in[(size_t)(r0 + r) * C + (c0 + c)];
  }
  __syncthreads();
  #pragma unroll
  for (int i = 0; i < 16; i++) {
    int idx = i * 256 + t; int c = idx >> 6, r = idx & 63;
    outh[(size_t)(c0 + c) * R + (r0 + r)] = (bf16_t)tile[r][c];
  }
}

// ---------------------------------------------------------------- GEMM1: QKV projection
__global__ __launch_bounds__(256) void k_gemm_qkv(
    const bf16_t* __restrict__ A, const bf16_t* __restrict__ Bt,
    const float* __restrict__ bias, bf16_t* __restrict__ qkv, bf16_t* __restrict__ vT) {
  __shared__ bf16_t As[128 * 32];
  __shared__ bf16_t Bs[128 * 32];
  const int tid = threadIdx.x, wid = tid >> 6, lane = tid & 63;
  const int bid = blockIdx.x;
  const int brow = bid & 31;
  const int bcol = bid >> 5;
  const int wr = wid >> 1, wc = wid & 1;
  const int lrow = lane & 15, lk = (lane >> 4) * 8;

  f32x4 acc[4][4] = {};

  const int c0 = wid * 64 + lane;
  const int c1 = 256 + wid * 64 + lane;
  const bf16_t* Ab = A + (size_t)(brow * 128) * DM;
  const bf16_t* Bb = Bt + (size_t)(bcol * 128) * DM;

  for (int k0 = 0; k0 < DM; k0 += 32) {
    gl_lds16(Ab + (size_t)(c0 >> 2) * DM + k0 + (c0 & 3) * 8, As + (wid * 64) * 8);
    gl_lds16(Ab + (size_t)(c1 >> 2) * DM + k0 + (c1 & 3) * 8, As + (256 + wid * 64) * 8);
    gl_lds16(Bb + (size_t)(c0 >> 2) * DM + k0 + (c0 & 3) * 8, Bs + (wid * 64) * 8);
    gl_lds16(Bb + (size_t)(c1 >> 2) * DM + k0 + (c1 & 3) * 8, Bs + (256 + wid * 64) * 8);
    __syncthreads();
    bf16x8 a[4], b[4];
    #pragma unroll
    for (int m = 0; m < 4; m++) a[m] = *(const bf16x8*)(As + (wr * 64 + m * 16 + lrow) * 32 + lk);
    #pragma unroll
    for (int n = 0; n < 4; n++) b[n] = *(const bf16x8*)(Bs + (wc * 64 + n * 16 + lrow) * 32 + lk);
    #pragma unroll
    for (int m = 0; m < 4; m++)
      #pragma unroll
      for (int n = 0; n < 4; n++)
        acc[m][n] = __builtin_amdgcn_mfma_f32_16x16x32_bf16(a[m], b[n], acc[m][n], 0, 0, 0);
    __syncthreads();
  }

  const int row0 = brow * 128 + wr * 64, col0 = bcol * 128 + wc * 64;
  #pragma unroll
  for (int n = 0; n < 4; n++) {
    int col = col0 + n * 16 + lrow;
    int which = col >> 10, rem = col & 1023;
    int h = rem >> 6, d = rem & 63;
    float bv = bias[col];
    float scl = (which == 0) ? 0.18033688011112042f : 1.0f;  // 0.125*log2e folded into Q
    if (which == 2) {
      bf16_t* ob = vT + ((size_t)h * HD + d) * N_TOK;
      #pragma unroll
      for (int m = 0; m < 4; m++) {
        int tok0 = row0 + m * 16 + (lane >> 4) * 4;
        bf16x4 pk;
        #pragma unroll
        for (int i = 0; i < 4; i++) pk[i] = (bf16_t)(acc[m][n][i] + bv);
        *(bf16x4*)(ob + tok0) = pk;
      }
    } else {
      bf16_t* ob = qkv + (size_t)(which * NH + h) * N_TOK * HD + d;
      #pragma unroll
      for (int m = 0; m < 4; m++)
        #pragma unroll
        for (int i = 0; i < 4; i++) {
          int row = row0 + m * 16 + (lane >> 4) * 4 + i;
          ob[(size_t)row * HD] = (bf16_t)((acc[m][n][i] + bv) * scl);
        }
    }
  }
}

// ---------------------------------------------------------------- attention
// 32x32x16 MFMA, 4 waves x 32 q-rows, swapped QK^T, static-max softmax
// (p = exp2(s), norm constant cancels in O/l), in-register P via
// pack + permlane32_swap, l on the MFMA pipe (ones-vector B).
// LDS chunk swizzle f(row) = (row&7) ^ (row>>3): spreads the 4 lanes sharing
// (row&7) across distinct bank groups -> conflict-free ds_read_b128
// (old f(row)=row&7 left a 4-way conflict on every fragment read).
__global__ __launch_bounds__(256, 4) void k_attn(
    const bf16_t* __restrict__ qkv, const bf16_t* __restrict__ vT,
    float* __restrict__ opart, float* __restrict__ lpart, int kv_chunk) {
  __shared__ bf16_t Kss[2][64 * 64];   // [kv][d], 16B-chunk xor-swizzled
  __shared__ bf16_t Vts[2][64 * 64];   // [d][kv], 16B-chunk xor-swizzled
  const int tid = threadIdx.x, wid = tid >> 6, lane = tid & 63;
  const int qb = blockIdx.x, h = blockIdx.y, kvs = blockIdx.z;
  const bf16_t* Q  = qkv + (size_t)h * N_TOK * HD;
  const bf16_t* K  = qkv + (size_t)(NH + h) * N_TOK * HD;
  const bf16_t* Vt = vT + (size_t)h * HD * N_TOK;
  const int L31 = lane & 31, h5 = lane >> 5;

  const int kv_lo = kvs * kv_chunk;
  const int kv_hi = kv_lo + kv_chunk;

  // staging: thread stages 16B chunks {tid, tid+256} of each 8KB tile;
  // dest linear, source chunk xor-swizzled with f(row) (matches read side).
  const int sr0 = tid >> 3;                              // rows 0..31 (+32 for 2nd)
  const int scA = (tid & 7) ^ (sr0 & 7) ^ (sr0 >> 3);    // f(sr0)
  const int scB = scA ^ 4;                               // f(sr0+32) = f(sr0)^4

#define STAGE(B, KV0) do {                                                                  \
    gl_lds16(K  + (size_t)((KV0) + sr0)      * HD + scA * 8, &Kss[B][wid * 512]);           \
    gl_lds16(K  + (size_t)((KV0) + 32 + sr0) * HD + scB * 8, &Kss[B][2048 + wid * 512]);    \
    gl_lds16(Vt + (size_t)sr0        * N_TOK + (KV0) + scA * 8, &Vts[B][wid * 512]);        \
    gl_lds16(Vt + (size_t)(32 + sr0) * N_TOK + (KV0) + scB * 8, &Vts[B][2048 + wid * 512]); \
  } while (0)

  // Q fragments (B-operand): lane holds Q[q = qb*128+wid*32+L31][dc*16 + h5*8 + j]
  bf16x8 aq[4];
  {
    int qrow = qb * 128 + wid * 32 + L31;
    #pragma unroll
    for (int dc = 0; dc < 4; dc++)
      aq[dc] = *(const bf16x8*)(Q + (size_t)qrow * HD + dc * 16 + h5 * 8);
  }
  f32x16 o0 = {}, o1 = {}, l_acc = {};
  f32x16 fz = {};
  asm volatile("" : "+v"(fz));   // pin zero block in registers (C-operand for S MFMAs)
  bf16x8 ones8;
  #pragma unroll
  for (int j = 0; j < 8; j++) ones8[j] = (bf16_t)1.0f;

  // read-side swizzle for row = L31 (block1) ; block2 adds ^4
  const int sw = (L31 & 7) ^ (L31 >> 3);

  STAGE(0, kv_lo);
  __syncthreads();

  int buf = 0;
  for (int kv0 = kv_lo; kv0 < kv_hi; kv0 += 64) {
    if (kv0 + 64 < kv_hi) STAGE(buf ^ 1, kv0 + 64);
    const bf16_t* kb = &Kss[buf][0] + L31 * 64;
    const bf16_t* vb = &Vts[buf][0] + L31 * 64;

    // S^T = K Q^T: two 32-kv blocks; lane holds S[kv][q=L31], 16 regs each
    __builtin_amdgcn_s_setprio(1);
    bf16x8 kf0 = *(const bf16x8*)(kb + (((0 + h5) ^ sw) * 8));
    bf16x8 kf1 = *(const bf16x8*)(kb + 2048 + (((0 + h5) ^ sw ^ 4) * 8));
    f32x16 s0 = __builtin_amdgcn_mfma_f32_32x32x16_bf16(kf0, aq[0], fz, 0, 0, 0);
    f32x16 s1 = __builtin_amdgcn_mfma_f32_32x32x16_bf16(kf1, aq[0], fz, 0, 0, 0);
    #pragma unroll
    for (int dc = 1; dc < 4; dc++) {
      kf0 = *(const bf16x8*)(kb + (((dc * 2 + h5) ^ sw) * 8));
      s0 = __builtin_amdgcn_mfma_f32_32x32x16_bf16(kf0, aq[dc], s0, 0, 0, 0);
      kf1 = *(const bf16x8*)(kb + 2048 + (((dc * 2 + h5) ^ sw ^ 4) * 8));
      s1 = __builtin_amdgcn_mfma_f32_32x32x16_bf16(kf1, aq[dc], s1, 0, 0, 0);
    }
    __builtin_amdgcn_s_setprio(0);

    bf16x8 ap0, ap1, ap2, ap3;
    softmax_blk(s0, ap0, ap1);   // slices 0,1 (kv 0..31)
    __builtin_amdgcn_s_setprio(1);
    {
      bf16x8 vf;
      vf = *(const bf16x8*)(vb + (((0 + h5) ^ sw) * 8));
      o0 = __builtin_amdgcn_mfma_f32_32x32x16_bf16(ap0, vf, o0, 0, 0, 0);
      vf = *(const bf16x8*)(vb + (((2 + h5) ^ sw) * 8));
      o0 = __builtin_amdgcn_mfma_f32_32x32x16_bf16(ap1, vf, o0, 0, 0, 0);
      vf = *(const bf16x8*)(vb + 2048 + (((0 + h5) ^ sw ^ 4) * 8));
      o1 = __builtin_amdgcn_mfma_f32_32x32x16_bf16(ap0, vf, o1, 0, 0, 0);
      vf = *(const bf16x8*)(vb + 2048 + (((2 + h5) ^ sw ^ 4) * 8));
      o1 = __builtin_amdgcn_mfma_f32_32x32x16_bf16(ap1, vf, o1, 0, 0, 0);
      l_acc = __builtin_amdgcn_mfma_f32_32x32x16_bf16(ap0, ones8, l_acc, 0, 0, 0);
      l_acc = __builtin_amdgcn_mfma_f32_32x32x16_bf16(ap1, ones8, l_acc, 0, 0, 0);
    }
    __builtin_amdgcn_s_setprio(0);
    softmax_blk(s1, ap2, ap3);   // slices 2,3 (kv 32..63)
    __builtin_amdgcn_s_setprio(1);
    {
      bf16x8 vf;
      vf = *(const bf16x8*)(vb + (((4 + h5) ^ sw) * 8));
      o0 = __builtin_amdgcn_mfma_f32_32x32x16_bf16(ap2, vf, o0, 0, 0, 0);
      vf = *(const bf16x8*)(vb + (((6 + h5) ^ sw) * 8));
      o0 = __builtin_amdgcn_mfma_f32_32x32x16_bf16(ap3, vf, o0, 0, 0, 0);
      vf = *(const bf16x8*)(vb + 2048 + (((4 + h5) ^ sw ^ 4) * 8));
      o1 = __builtin_amdgcn_mfma_f32_32x32x16_bf16(ap2, vf, o1, 0, 0, 0);
      vf = *(const bf16x8*)(vb + 2048 + (((6 + h5) ^ sw ^ 4) * 8));
      o1 = __builtin_amdgcn_mfma_f32_32x32x16_bf16(ap3, vf, o1, 0, 0, 0);
      l_acc = __builtin_amdgcn_mfma_f32_32x32x16_bf16(ap2, ones8, l_acc, 0, 0, 0);
      l_acc = __builtin_amdgcn_mfma_f32_32x32x16_bf16(ap3, ones8, l_acc, 0, 0, 0);
    }
    __builtin_amdgcn_s_setprio(0);

    __syncthreads();
    buf ^= 1;
  }
#undef STAGE

  // l[q] sits (replicated across the 32 cols) in l_acc at row q=(r&3)+8*(r>>2)+4*h5
  if (L31 == 0) {
    float* lp = lpart + ((size_t)kvs * NH + h) * N_TOK + qb * 128 + wid * 32;
    #pragma unroll
    for (int r = 0; r < 16; r++)
      lp[(r & 3) + 8 * (r >> 2) + 4 * h5] = l_acc[r];
  }

  // O: col = d = dblk*32 + L31, row = q -> coalesced [tok][DM]
  float* op = opart + (size_t)kvs * N_TOK * DM;
  #pragma unroll
  for (int r = 0; r < 16; r++) {
    int q32 = (r & 3) + 8 * (r >> 2) + 4 * h5;
    size_t base = (size_t)(qb * 128 + wid * 32 + q32) * DM + h * HD + L31;
    op[base] = o0[r];
    op[base + 32] = o1[r];
  }
}

// ---------------------------------------------------------------- combine kv parts -> bf16
__global__ __launch_bounds__(256) void k_combine(
    const float* __restrict__ opart, const float* __restrict__ lpart,
    bf16_t* __restrict__ oattn, int nsplit) {
  const int row = blockIdx.x, tid = threadIdx.x;
  const int col = tid * 4;
  const int h = col >> 6;
  const size_t idx = (size_t)row * DM + col;
  float4 a = *(const float4*)(opart + idx);
  float lsum = lpart[(size_t)h * N_TOK + row];
  for (int p = 1; p < nsplit; p++) {
    float4 b = *(const float4*)(opart + (size_t)p * N_TOK * DM + idx);
    a.x += b.x; a.y += b.y; a.z += b.z; a.w += b.w;
    lsum += lpart[((size_t)p * NH + h) * N_TOK + row];
  }
  float rl = 1.0f / lsum;
  bf16x4 hv;
  hv[0] = (bf16_t)(a.x * rl); hv[1] = (bf16_t)(a.y * rl);
  hv[2] = (bf16_t)(a.z * rl); hv[3] = (bf16_t)(a.w * rl);
  *(bf16x4*)(oattn + idx) = hv;
}

// ---------------------------------------------------------------- GEMM2: output projection (bf16)
__global__ __launch_bounds__(256) void k_gemm_out(
    const bf16_t* __restrict__ A, const bf16_t* __restrict__ Bt,
    const float* __restrict__ bias, float* __restrict__ out) {
  __shared__ bf16_t As[128 * 32];
  __shared__ bf16_t Bs[128 * 32];
  const int tid = threadIdx.x, wid = tid >> 6, lane = tid & 63;
  const int bid = blockIdx.x;
  const int brow = bid & 31;  // 32 row tiles
  const int bcol = bid >> 5;  // 8 col tiles
  const int wr = wid >> 1, wc = wid & 1;
  const int lrow = lane & 15, lk = (lane >> 4) * 8;

  f32x4 acc[4][4] = {};

  const int c0 = wid * 64 + lane;
  const int c1 = 256 + wid * 64 + lane;
  const bf16_t* Ab = A + (size_t)(brow * 128) * DM;
  const bf16_t* Bb = Bt + (size_t)(bcol * 128) * DM;

  for (int k0 = 0; k0 < DM; k0 += 32) {
    gl_lds16(Ab + (size_t)(c0 >> 2) * DM + k0 + (c0 & 3) * 8, As + (wid * 64) * 8);
    gl_lds16(Ab + (size_t)(c1 >> 2) * DM + k0 + (c1 & 3) * 8, As + (256 + wid * 64) * 8);
    gl_lds16(Bb + (size_t)(c0 >> 2) * DM + k0 + (c0 & 3) * 8, Bs + (wid * 64) * 8);
    gl_lds16(Bb + (size_t)(c1 >> 2) * DM + k0 + (c1 & 3) * 8, Bs + (256 + wid * 64) * 8);
    __syncthreads();
    bf16x8 a[4], b[4];
    #pragma unroll
    for (int m = 0; m < 4; m++) a[m] = *(const bf16x8*)(As + (wr * 64 + m * 16 + lrow) * 32 + lk);
    #pragma unroll
    for (int n = 0; n < 4; n++) b[n] = *(const bf16x8*)(Bs + (wc * 64 + n * 16 + lrow) * 32 + lk);
    #pragma unroll
    for (int m = 0; m < 4; m++)
      #pragma unroll
      for (int n = 0; n < 4; n++)
        acc[m][n] = __builtin_amdgcn_mfma_f32_16x16x32_bf16(a[m], b[n], acc[m][n], 0, 0, 0);
    __syncthreads();
  }

  const int row0 = brow * 128 + wr * 64, col0 = bcol * 128 + wc * 64;
  #pragma unroll
  for (int n = 0; n < 4; n++) {
    int col = col0 + n * 16 + lrow;
    float bv = bias[col];
    #pragma unroll
    for (int m = 0; m < 4; m++)
      #pragma unroll
      for (int i = 0; i < 4; i++) {
        int row = row0 + m * 16 + (lane >> 4) * 4 + i;
        out[(size_t)row * DM + col] = acc[m][n][i] + bv;
      }
  }
}

// ---------------------------------------------------------------- launcher
extern "C" void kernel_launch(void* const* d_in, const int* in_sizes, int n_in,
                              void* d_out, int out_size, void* d_ws, size_t ws_size,
                              hipStream_t stream) {
  const float* x     = (const float*)d_in[0];
  const float* w_qkv = (const float*)d_in[1];
  const float* b_qkv = (const float*)d_in[2];
  const float* w_out = (const float*)d_in[3];
  const float* b_out = (const float*)d_in[4];
  float* out = (float*)d_out;

  char* ws = (char*)d_ws;
  bf16_t* qkv     = (bf16_t*)(ws);                       // 24 MB (Q,K rows; V third = vT)
  bf16_t* x_bf    = (bf16_t*)(ws + 25165824);            // 8 MB
  bf16_t* wqkv_t  = (bf16_t*)(ws + 33554432);            // 6 MB
  bf16_t* wout_t  = (bf16_t*)(ws + 39845888);            // 2 MB
  bf16_t* attn    = (bf16_t*)(ws + 41943040);            // 8 MB
  float*  lpart   = (float*)(ws + 50331648);             // 1 MB
  float*  opart   = (float*)(ws + 51380224);             // 16/32 MB
  bf16_t* vT      = qkv + (size_t)2 * NH * N_TOK * HD;   // overlay V third: [h][d][tok]

  const size_t OPBASE = 51380224ull;
  const size_t PART = (size_t)N_TOK * DM * 4;            // 16 MB per O-part
  const int nsplit = (ws_size >= OPBASE + 2 * PART) ? 2 : 1;

  k_cvt_x<<<2048, 256, 0, stream>>>(x, x_bf);
  k_transpose_cvt<<<dim3(48, 16), 256, 0, stream>>>(w_qkv, wqkv_t, DM, D3);
  k_transpose_cvt<<<dim3(16, 16), 256, 0, stream>>>(w_out, wout_t, DM, DM);
  k_gemm_qkv<<<768, 256, 0, stream>>>(x_bf, wqkv_t, b_qkv, qkv, vT);
  k_attn<<<dim3(32, 16, nsplit), 256, 0, stream>>>(qkv, vT, opart, lpart, N_TOK / nsplit);
  k_combine<<<4096, 256, 0, stream>>>(opart, lpart, attn, nsplit);
  k_gemm_out<<<256, 256, 0, stream>>>(attn, wout_t, b_out, out);
}

// Round 14
// 163.717 us; speedup vs baseline: 1.1853x; 1.1853x over previous
//
#include <hip/hip_runtime.h>
#include <hip/hip_bf16.h>

using bf16_t = __bf16;
using bf16x4 = __attribute__((ext_vector_type(4))) __bf16;
using bf16x8 = __attribute__((ext_vector_type(8))) __bf16;
using f32x4  = __attribute__((ext_vector_type(4))) float;
using f32x16 = __attribute__((ext_vector_type(16))) float;
using u32x2  = __attribute__((ext_vector_type(2))) unsigned;

#define N_TOK 4096
#define DM    1024
#define NH    16
#define HD    64
#define D3    3072

// raw v_exp_f32 (skip OCML's denormal-range fixup; inputs bounded >> -126)
#if __has_builtin(__builtin_amdgcn_exp2f)
#define EXP2(x) __builtin_amdgcn_exp2f(x)
#else
extern "C" float __ocml_native_exp2_f32(float);
#define EXP2(x) __ocml_native_exp2_f32(x)
#endif

// ---------------------------------------------------------------- helpers
__device__ __forceinline__ void gl_lds16(const void* g, void* l) {
  __builtin_amdgcn_global_load_lds((const __attribute__((address_space(1))) void*)g,
                                   (__attribute__((address_space(3))) void*)l, 16, 0, 0);
}

__device__ __forceinline__ unsigned pkbf(float a, float b) {
  unsigned short la = __builtin_bit_cast(unsigned short, (bf16_t)a);
  unsigned short lb = __builtin_bit_cast(unsigned short, (bf16_t)b);
  return (unsigned)la | ((unsigned)lb << 16);
}

__device__ __forceinline__ bf16x8 mk8(unsigned a, unsigned b, unsigned c, unsigned d) {
  union { unsigned u[4]; bf16x8 v; } t;
  t.u[0] = a; t.u[1] = b; t.u[2] = c; t.u[3] = d;
  return t.v;
}

// softmax for one 32-kv block held as f32x16 (32x32 C-layout), producing the
// two 16-kv A-fragment slices for PV via pack + permlane32_swap (T12).
// l is NOT summed here: it is accumulated on the MFMA pipe via a ones-vector.
__device__ __forceinline__ void softmax_blk(const f32x16& sv, bf16x8& apA, bf16x8& apB) {
  float pp[16];
  #pragma unroll
  for (int r = 0; r < 16; r++) pp[r] = EXP2(sv[r]);
  unsigned w00 = pkbf(pp[0], pp[1]),   w01 = pkbf(pp[2], pp[3]);
  unsigned w10 = pkbf(pp[4], pp[5]),   w11 = pkbf(pp[6], pp[7]);
  unsigned w20 = pkbf(pp[8], pp[9]),   w21 = pkbf(pp[10], pp[11]);
  unsigned w30 = pkbf(pp[12], pp[13]), w31 = pkbf(pp[14], pp[15]);
  u32x2 r00 = __builtin_amdgcn_permlane32_swap(w00, w10, false, false);
  u32x2 r01 = __builtin_amdgcn_permlane32_swap(w01, w11, false, false);
  u32x2 r10 = __builtin_amdgcn_permlane32_swap(w20, w30, false, false);
  u32x2 r11 = __builtin_amdgcn_permlane32_swap(w21, w31, false, false);
  apA = mk8(r00[0], r01[0], r00[1], r01[1]);   // slice p=0 (kv +0..15)
  apB = mk8(r10[0], r11[0], r10[1], r11[1]);   // slice p=1 (kv +16..31)
}

// ---------------------------------------------------------------- prep kernels
__global__ void k_cvt_x(const float* __restrict__ x, bf16_t* __restrict__ xb) {
  int i = (blockIdx.x * blockDim.x + threadIdx.x) * 8;
  float4 f0 = *(const float4*)(x + i);
  float4 f1 = *(const float4*)(x + i + 4);
  bf16x8 v;
  v[0] = (bf16_t)f0.x; v[1] = (bf16_t)f0.y; v[2] = (bf16_t)f0.z; v[3] = (bf16_t)f0.w;
  v[4] = (bf16_t)f1.x; v[5] = (bf16_t)f1.y; v[6] = (bf16_t)f1.z; v[7] = (bf16_t)f1.w;
  *(bf16x8*)(xb + i) = v;
}

// in [R][C] f32  ->  out [C][R] bf16
__global__ void k_transpose_cvt(const float* __restrict__ in, bf16_t* __restrict__ outh,
                                int R, int C) {
  __shared__ float tile[64][65];
  int r0 = blockIdx.y * 64, c0 = blockIdx.x * 64;
  int t = threadIdx.x;
  #pragma unroll
  for (int i = 0; i < 16; i++) {
    int idx = i * 256 + t; int r = idx >> 6, c = idx & 63;
    tile[r][c] = in[(size_t)(r0 + r) * C + (c0 + c)];
  }
  __syncthreads();
  #pragma unroll
  for (int i = 0; i < 16; i++) {
    int idx = i * 256 + t; int c = idx >> 6, r = idx & 63;
    outh[(size_t)(c0 + c) * R + (r0 + r)] = (bf16_t)tile[r][c];
  }
}

// ---------------------------------------------------------------- GEMM1: QKV projection
__global__ __launch_bounds__(256) void k_gemm_qkv(
    const bf16_t* __restrict__ A, const bf16_t* __restrict__ Bt,
    const float* __restrict__ bias, bf16_t* __restrict__ qkv, bf16_t* __restrict__ vT) {
  __shared__ bf16_t As[128 * 32];
  __shared__ bf16_t Bs[128 * 32];
  const int tid = threadIdx.x, wid = tid >> 6, lane = tid & 63;
  const int bid = blockIdx.x;
  const int brow = bid & 31;
  const int bcol = bid >> 5;
  const int wr = wid >> 1, wc = wid & 1;
  const int lrow = lane & 15, lk = (lane >> 4) * 8;

  f32x4 acc[4][4] = {};

  const int c0 = wid * 64 + lane;
  const int c1 = 256 + wid * 64 + lane;
  const bf16_t* Ab = A + (size_t)(brow * 128) * DM;
  const bf16_t* Bb = Bt + (size_t)(bcol * 128) * DM;

  for (int k0 = 0; k0 < DM; k0 += 32) {
    gl_lds16(Ab + (size_t)(c0 >> 2) * DM + k0 + (c0 & 3) * 8, As + (wid * 64) * 8);
    gl_lds16(Ab + (size_t)(c1 >> 2) * DM + k0 + (c1 & 3) * 8, As + (256 + wid * 64) * 8);
    gl_lds16(Bb + (size_t)(c0 >> 2) * DM + k0 + (c0 & 3) * 8, Bs + (wid * 64) * 8);
    gl_lds16(Bb + (size_t)(c1 >> 2) * DM + k0 + (c1 & 3) * 8, Bs + (256 + wid * 64) * 8);
    __syncthreads();
    bf16x8 a[4], b[4];
    #pragma unroll
    for (int m = 0; m < 4; m++) a[m] = *(const bf16x8*)(As + (wr * 64 + m * 16 + lrow) * 32 + lk);
    #pragma unroll
    for (int n = 0; n < 4; n++) b[n] = *(const bf16x8*)(Bs + (wc * 64 + n * 16 + lrow) * 32 + lk);
    #pragma unroll
    for (int m = 0; m < 4; m++)
      #pragma unroll
      for (int n = 0; n < 4; n++)
        acc[m][n] = __builtin_amdgcn_mfma_f32_16x16x32_bf16(a[m], b[n], acc[m][n], 0, 0, 0);
    __syncthreads();
  }

  const int row0 = brow * 128 + wr * 64, col0 = bcol * 128 + wc * 64;
  #pragma unroll
  for (int n = 0; n < 4; n++) {
    int col = col0 + n * 16 + lrow;
    int which = col >> 10, rem = col & 1023;
    int h = rem >> 6, d = rem & 63;
    float bv = bias[col];
    float scl = (which == 0) ? 0.18033688011112042f : 1.0f;  // 0.125*log2e folded into Q
    if (which == 2) {
      bf16_t* ob = vT + ((size_t)h * HD + d) * N_TOK;
      #pragma unroll
      for (int m = 0; m < 4; m++) {
        int tok0 = row0 + m * 16 + (lane >> 4) * 4;
        bf16x4 pk;
        #pragma unroll
        for (int i = 0; i < 4; i++) pk[i] = (bf16_t)(acc[m][n][i] + bv);
        *(bf16x4*)(ob + tok0) = pk;
      }
    } else {
      bf16_t* ob = qkv + (size_t)(which * NH + h) * N_TOK * HD + d;
      #pragma unroll
      for (int m = 0; m < 4; m++)
        #pragma unroll
        for (int i = 0; i < 4; i++) {
          int row = row0 + m * 16 + (lane >> 4) * 4 + i;
          ob[(size_t)row * HD] = (bf16_t)((acc[m][n][i] + bv) * scl);
        }
    }
  }
}

// ---------------------------------------------------------------- attention
// R10 core (measured best): 32x32x16 MFMA, 4 waves x 32 q-rows, swapped QK^T,
// static-max softmax, in-register P via pack + permlane32_swap, l on the MFMA
// pipe (ones-vector B), double-buffered LDS, r7 chunk swizzle (4-way conflict
// is hidden — R13 proved removing it doesn't help and hurts HBM).
// New: XCD-bijective block swizzle (qb-blocks sharing (h,kvs) K/V panels land
// on one XCD -> L2-resident K/V); bf16 O-partials (halved write traffic).
__global__ __launch_bounds__(256, 4) void k_attn(
    const bf16_t* __restrict__ qkv, const bf16_t* __restrict__ vT,
    bf16_t* __restrict__ opart, float* __restrict__ lpart, int kv_chunk) {
  __shared__ bf16_t Kss[2][64 * 64];   // [kv][d], 16B-chunk xor-swizzled
  __shared__ bf16_t Vts[2][64 * 64];   // [d][kv], 16B-chunk xor-swizzled
  const int tid = threadIdx.x, wid = tid >> 6, lane = tid & 63;
  // XCD-aware bijective swizzle (gridDim.x % 8 == 0)
  const int chunkx = gridDim.x >> 3;
  const int gid = blockIdx.x;
  const int wgid = (gid & 7) * chunkx + (gid >> 3);
  const int qb = wgid & 31, h = (wgid >> 5) & 15, kvs = wgid >> 9;
  const bf16_t* Q  = qkv + (size_t)h * N_TOK * HD;
  const bf16_t* K  = qkv + (size_t)(NH + h) * N_TOK * HD;
  const bf16_t* Vt = vT + (size_t)h * HD * N_TOK;
  const int L31 = lane & 31, h5 = lane >> 5, r7 = L31 & 7;

  const int kv_lo = kvs * kv_chunk;
  const int kv_hi = kv_lo + kv_chunk;

  // staging: thread stages 16B chunks {tid, tid+256} of each 8KB tile;
  // dest linear, source chunk xor-swizzled (involution, matches read side)
  const int sr0 = tid >> 3;               // rows 0..31 (+32 for 2nd chunk)
  const int sc0 = (tid & 7) ^ (sr0 & 7);  // (row&7) invariant under +32

#define STAGE(B, KV0) do {                                                                  \
    gl_lds16(K  + (size_t)((KV0) + sr0)      * HD + sc0 * 8, &Kss[B][wid * 512]);           \
    gl_lds16(K  + (size_t)((KV0) + 32 + sr0) * HD + sc0 * 8, &Kss[B][2048 + wid * 512]);    \
    gl_lds16(Vt + (size_t)sr0        * N_TOK + (KV0) + sc0 * 8, &Vts[B][wid * 512]);        \
    gl_lds16(Vt + (size_t)(32 + sr0) * N_TOK + (KV0) + sc0 * 8, &Vts[B][2048 + wid * 512]); \
  } while (0)

  // Q fragments (B-operand): lane holds Q[q = qb*128+wid*32+L31][dc*16 + h5*8 + j]
  bf16x8 aq[4];
  {
    int qrow = qb * 128 + wid * 32 + L31;
    #pragma unroll
    for (int dc = 0; dc < 4; dc++)
      aq[dc] = *(const bf16x8*)(Q + (size_t)qrow * HD + dc * 16 + h5 * 8);
  }
  f32x16 o0 = {}, o1 = {}, l_acc = {};
  f32x16 fz = {};
  asm volatile("" : "+v"(fz));   // pin zero block in registers (C-operand for S MFMAs)
  bf16x8 ones8;
  #pragma unroll
  for (int j = 0; j < 8; j++) ones8[j] = (bf16_t)1.0f;

  STAGE(0, kv_lo);
  __syncthreads();

  int buf = 0;
  for (int kv0 = kv_lo; kv0 < kv_hi; kv0 += 64) {
    if (kv0 + 64 < kv_hi) STAGE(buf ^ 1, kv0 + 64);
    const bf16_t* kb = &Kss[buf][0] + L31 * 64;
    const bf16_t* vb = &Vts[buf][0] + L31 * 64;

    // S^T = K Q^T: two 32-kv blocks; lane holds S[kv][q=L31], 16 regs each
    __builtin_amdgcn_s_setprio(1);
    bf16x8 kf0 = *(const bf16x8*)(kb + (((0 + h5) ^ r7) * 8));
    bf16x8 kf1 = *(const bf16x8*)(kb + 2048 + (((0 + h5) ^ r7) * 8));
    f32x16 s0 = __builtin_amdgcn_mfma_f32_32x32x16_bf16(kf0, aq[0], fz, 0, 0, 0);
    f32x16 s1 = __builtin_amdgcn_mfma_f32_32x32x16_bf16(kf1, aq[0], fz, 0, 0, 0);
    #pragma unroll
    for (int dc = 1; dc < 4; dc++) {
      kf0 = *(const bf16x8*)(kb + (((dc * 2 + h5) ^ r7) * 8));
      s0 = __builtin_amdgcn_mfma_f32_32x32x16_bf16(kf0, aq[dc], s0, 0, 0, 0);
      kf1 = *(const bf16x8*)(kb + 2048 + (((dc * 2 + h5) ^ r7) * 8));
      s1 = __builtin_amdgcn_mfma_f32_32x32x16_bf16(kf1, aq[dc], s1, 0, 0, 0);
    }
    __builtin_amdgcn_s_setprio(0);

    bf16x8 ap0, ap1, ap2, ap3;
    softmax_blk(s0, ap0, ap1);   // slices 0,1 (kv 0..31)
    __builtin_amdgcn_s_setprio(1);
    {
      bf16x8 vf;
      vf = *(const bf16x8*)(vb + (((0 + h5) ^ r7) * 8));
      o0 = __builtin_amdgcn_mfma_f32_32x32x16_bf16(ap0, vf, o0, 0, 0, 0);
      vf = *(const bf16x8*)(vb + (((2 + h5) ^ r7) * 8));
      o0 = __builtin_amdgcn_mfma_f32_32x32x16_bf16(ap1, vf, o0, 0, 0, 0);
      vf = *(const bf16x8*)(vb + 2048 + (((0 + h5) ^ r7) * 8));
      o1 = __builtin_amdgcn_mfma_f32_32x32x16_bf16(ap0, vf, o1, 0, 0, 0);
      vf = *(const bf16x8*)(vb + 2048 + (((2 + h5) ^ r7) * 8));
      o1 = __builtin_amdgcn_mfma_f32_32x32x16_bf16(ap1, vf, o1, 0, 0, 0);
      l_acc = __builtin_amdgcn_mfma_f32_32x32x16_bf16(ap0, ones8, l_acc, 0, 0, 0);
      l_acc = __builtin_amdgcn_mfma_f32_32x32x16_bf16(ap1, ones8, l_acc, 0, 0, 0);
    }
    __builtin_amdgcn_s_setprio(0);
    softmax_blk(s1, ap2, ap3);   // slices 2,3 (kv 32..63)
    __builtin_amdgcn_s_setprio(1);
    {
      bf16x8 vf;
      vf = *(const bf16x8*)(vb + (((4 + h5) ^ r7) * 8));
      o0 = __builtin_amdgcn_mfma_f32_32x32x16_bf16(ap2, vf, o0, 0, 0, 0);
      vf = *(const bf16x8*)(vb + (((6 + h5) ^ r7) * 8));
      o0 = __builtin_amdgcn_mfma_f32_32x32x16_bf16(ap3, vf, o0, 0, 0, 0);
      vf = *(const bf16x8*)(vb + 2048 + (((4 + h5) ^ r7) * 8));
      o1 = __builtin_amdgcn_mfma_f32_32x32x16_bf16(ap2, vf, o1, 0, 0, 0);
      vf = *(const bf16x8*)(vb + 2048 + (((6 + h5) ^ r7) * 8));
      o1 = __builtin_amdgcn_mfma_f32_32x32x16_bf16(ap3, vf, o1, 0, 0, 0);
      l_acc = __builtin_amdgcn_mfma_f32_32x32x16_bf16(ap2, ones8, l_acc, 0, 0, 0);
      l_acc = __builtin_amdgcn_mfma_f32_32x32x16_bf16(ap3, ones8, l_acc, 0, 0, 0);
    }
    __builtin_amdgcn_s_setprio(0);

    __syncthreads();
    buf ^= 1;
  }
#undef STAGE

  // l[q] sits (replicated across the 32 cols) in l_acc at row q=(r&3)+8*(r>>2)+4*h5
  if (L31 == 0) {
    float* lp = lpart + ((size_t)kvs * NH + h) * N_TOK + qb * 128 + wid * 32;
    #pragma unroll
    for (int r = 0; r < 16; r++)
      lp[(r & 3) + 8 * (r >> 2) + 4 * h5] = l_acc[r];
  }

  // O partials in bf16: col = d = dblk*32 + L31, row = q -> coalesced [tok][DM]
  bf16_t* op = opart + (size_t)kvs * N_TOK * DM;
  #pragma unroll
  for (int r = 0; r < 16; r++) {
    int q32 = (r & 3) + 8 * (r >> 2) + 4 * h5;
    size_t base = (size_t)(qb * 128 + wid * 32 + q32) * DM + h * HD + L31;
    op[base] = (bf16_t)o0[r];
    op[base + 32] = (bf16_t)o1[r];
  }
}

// ---------------------------------------------------------------- combine kv parts -> bf16
__global__ __launch_bounds__(256) void k_combine(
    const bf16_t* __restrict__ opart, const float* __restrict__ lpart,
    bf16_t* __restrict__ oattn, int nsplit) {
  const int row = blockIdx.x, tid = threadIdx.x;
  const int col = tid * 4;
  const int h = col >> 6;
  const size_t idx = (size_t)row * DM + col;
  bf16x4 b0 = *(const bf16x4*)(opart + idx);
  float a[4] = {(float)b0[0], (float)b0[1], (float)b0[2], (float)b0[3]};
  float lsum = lpart[(size_t)h * N_TOK + row];
  for (int p = 1; p < nsplit; p++) {
    bf16x4 bp = *(const bf16x4*)(opart + (size_t)p * N_TOK * DM + idx);
    #pragma unroll
    for (int j = 0; j < 4; j++) a[j] += (float)bp[j];
    lsum += lpart[((size_t)p * NH + h) * N_TOK + row];
  }
  float rl = 1.0f / lsum;
  bf16x4 hv;
  #pragma unroll
  for (int j = 0; j < 4; j++) hv[j] = (bf16_t)(a[j] * rl);
  *(bf16x4*)(oattn + idx) = hv;
}

// ---------------------------------------------------------------- GEMM2: output projection (bf16)
// 64x128 tile, grid 512 = 2 blocks/CU (128x128 was 1/CU -> barrier drains exposed)
__global__ __launch_bounds__(256) void k_gemm_out(
    const bf16_t* __restrict__ A, const bf16_t* __restrict__ Bt,
    const float* __restrict__ bias, float* __restrict__ out) {
  __shared__ bf16_t As[64 * 32];    // 4 KB
  __shared__ bf16_t Bs[128 * 32];   // 8 KB
  const int tid = threadIdx.x, wid = tid >> 6, lane = tid & 63;
  const int bid = blockIdx.x;
  const int brow = bid & 63;  // 64 row tiles of 64
  const int bcol = bid >> 6;  // 8 col tiles of 128
  const int wr = wid >> 1, wc = wid & 1;
  const int lrow = lane & 15, lk = (lane >> 4) * 8;

  f32x4 acc[2][4] = {};

  const int c0 = wid * 64 + lane;   // chunk ids 0..255
  const bf16_t* Ab = A + (size_t)(brow * 64) * DM;
  const bf16_t* Bb = Bt + (size_t)(bcol * 128) * DM;

  for (int k0 = 0; k0 < DM; k0 += 32) {
    gl_lds16(Ab + (size_t)(c0 >> 2) * DM + k0 + (c0 & 3) * 8, As + (wid * 64) * 8);
    gl_lds16(Bb + (size_t)(c0 >> 2) * DM + k0 + (c0 & 3) * 8, Bs + (wid * 64) * 8);
    gl_lds16(Bb + (size_t)((c0 + 256) >> 2) * DM + k0 + (c0 & 3) * 8, Bs + (256 + wid * 64) * 8);
    __syncthreads();
    bf16x8 a[2], b[4];
    #pragma unroll
    for (int m = 0; m < 2; m++) a[m] = *(const bf16x8*)(As + (wr * 32 + m * 16 + lrow) * 32 + lk);
    #pragma unroll
    for (int n = 0; n < 4; n++) b[n] = *(const bf16x8*)(Bs + (wc * 64 + n * 16 + lrow) * 32 + lk);
    #pragma unroll
    for (int m = 0; m < 2; m++)
      #pragma unroll
      for (int n = 0; n < 4; n++)
        acc[m][n] = __builtin_amdgcn_mfma_f32_16x16x32_bf16(a[m], b[n], acc[m][n], 0, 0, 0);
    __syncthreads();
  }

  const int row0 = brow * 64 + wr * 32, col0 = bcol * 128 + wc * 64;
  #pragma unroll
  for (int n = 0; n < 4; n++) {
    int col = col0 + n * 16 + lrow;
    float bv = bias[col];
    #pragma unroll
    for (int m = 0; m < 2; m++)
      #pragma unroll
      for (int i = 0; i < 4; i++) {
        int row = row0 + m * 16 + (lane >> 4) * 4 + i;
        out[(size_t)row * DM + col] = acc[m][n][i] + bv;
      }
  }
}

// ---------------------------------------------------------------- launcher
extern "C" void kernel_launch(void* const* d_in, const int* in_sizes, int n_in,
                              void* d_out, int out_size, void* d_ws, size_t ws_size,
                              hipStream_t stream) {
  const float* x     = (const float*)d_in[0];
  const float* w_qkv = (const float*)d_in[1];
  const float* b_qkv = (const float*)d_in[2];
  const float* w_out = (const float*)d_in[3];
  const float* b_out = (const float*)d_in[4];
  float* out = (float*)d_out;

  char* ws = (char*)d_ws;
  bf16_t* qkv     = (bf16_t*)(ws);                       // 24 MB (Q,K rows; V third = vT)
  bf16_t* x_bf    = (bf16_t*)(ws + 25165824);            // 8 MB
  bf16_t* wqkv_t  = (bf16_t*)(ws + 33554432);            // 6 MB
  bf16_t* wout_t  = (bf16_t*)(ws + 39845888);            // 2 MB
  bf16_t* attn    = (bf16_t*)(ws + 41943040);            // 8 MB
  float*  lpart   = (float*)(ws + 50331648);             // 1 MB
  bf16_t* opart   = (bf16_t*)(ws + 51380224);            // 8/16 MB (bf16 partials)
  bf16_t* vT      = qkv + (size_t)2 * NH * N_TOK * HD;   // overlay V third: [h][d][tok]

  const size_t OPBASE = 51380224ull;
  const size_t PART = (size_t)N_TOK * DM * 2;            // 8 MB per bf16 O-part
  const int nsplit = (ws_size >= OPBASE + 2 * PART) ? 2 : 1;

  k_cvt_x<<<2048, 256, 0, stream>>>(x, x_bf);
  k_transpose_cvt<<<dim3(48, 16), 256, 0, stream>>>(w_qkv, wqkv_t, DM, D3);
  k_transpose_cvt<<<dim3(16, 16), 256, 0, stream>>>(w_out, wout_t, DM, DM);
  k_gemm_qkv<<<768, 256, 0, stream>>>(x_bf, wqkv_t, b_qkv, qkv, vT);
  k_attn<<<512 * nsplit, 256, 0, stream>>>(qkv, vT, opart, lpart, N_TOK / nsplit);
  k_combine<<<4096, 256, 0, stream>>>(opart, lpart, attn, nsplit);
  k_gemm_out<<<512, 256, 0, stream>>>(attn, wout_t, b_out, out);
}